// Round 4
// baseline (346.068 us; speedup 1.0000x reference)
//
#include <hip/hip_runtime.h>
#include <hip/hip_bf16.h>
#include <math.h>

#define Bn 16
#define Cc 256
#define Oo 128
#define HWn 4096
#define Ntot 65536   // Bn*HWn
#define BK 64
#define GRID 512     // 16 batches x 32 hw-tiles; exactly 2 blocks/CU on 256 CUs

typedef __attribute__((ext_vector_type(8))) __bf16 bf16x8;
typedef __attribute__((ext_vector_type(4))) float f32x4;

__device__ __forceinline__ unsigned short f2bf(float f) {
    unsigned u = __builtin_bit_cast(unsigned, f);
    u = (u + 0x7FFFu + ((u >> 16) & 1u)) >> 16;
    return (unsigned short)u;
}

// Single fused kernel, plain launch (graph-capture safe), hand-rolled grid barrier.
// Residency guarantee: __launch_bounds__(256,2) caps VGPR at 256 -> 2 blocks/CU;
// LDS ~41.7 KB -> 3 blocks/CU; grid=512 = 2x256 CUs -> all blocks resident.
//   phase A: GEMM wg@g and wx@x (K=256) into registers (two 128x128 o-by-hw tiles)
//            (biases cancel exactly under training-mode BN and are dropped)
//   phase B: block-local BN1 stat partials -> device atomicAdd into gstat[512]
//   BAR 1
//   phase C: every block builds the 128-channel BN coef table from gstat (2 KB)
//   phase D: psi from registers -> s[128 pixels] in LDS; psi stats -> atomicAdd psum[2]
//   BAR 2
//   phase E: sigmoid coefs from psum; out = x * sigmoid(ps*s+psh)  (x tile L3-hot)
__global__ __launch_bounds__(256, 2)
void fused(const float* __restrict__ gin, const float* __restrict__ xin,
           const float* __restrict__ wgw, const float* __restrict__ wxw,
           const float* __restrict__ wg_gamma, const float* __restrict__ wg_beta,
           const float* __restrict__ wx_gamma, const float* __restrict__ wx_beta,
           const float* __restrict__ psi_w, const float* __restrict__ psi_gamma,
           const float* __restrict__ psi_beta,
           float* __restrict__ outp,
           float* __restrict__ gstat,    // 512 floats, pre-zeroed: [(z<<7|o)<<1 | s]
           float* __restrict__ psum,     // 2 floats, pre-zeroed
           unsigned* __restrict__ bar)   // 2 counters, pre-zeroed
{
    __shared__ short A_s[128][72];        // [o][c] bf16, row stride 144 B
    __shared__ unsigned int B_s[32][129]; // [c2][hw] packed (bf16 c, bf16 c+1)
    __shared__ float red[8][129];         // stat partials / psi partials
    __shared__ float sfin[128];           // per-pixel s for this tile
    __shared__ float lgs[128], lxs[128], lch[128], lpw[128];
    __shared__ float rr[4];
    __shared__ float pcl[2];

    const int t    = threadIdx.x;
    const int bid  = blockIdx.x;          // 0..511
    const int b    = bid >> 5;
    const int hw0  = (bid & 31) * 128;
    const int lane = t & 63;
    const int wv   = t >> 6;
    const int m0   = (wv & 1) * 64;   // o offset in tile
    const int n0   = (wv >> 1) * 64;  // hw offset in tile
    const int q    = lane >> 4;
    const int r    = lane & 15;

    // staging indices
    const int su  = t & 31;   // B: hw block (hw = su*4)
    const int sc2 = t >> 5;   // B: c-pair row 0..7
    const int au  = t & 15;   // A: c block (c = au*4)
    const int ao  = t >> 4;   // A: o 0..15 (step 16)

    f32x4 accg[4][4], accx[4][4];
#pragma unroll
    for (int i = 0; i < 4; i++)
#pragma unroll
        for (int j = 0; j < 4; j++) {
            accg[i][j] = (f32x4){0.f, 0.f, 0.f, 0.f};
            accx[i][j] = (f32x4){0.f, 0.f, 0.f, 0.f};
        }

    float4 bv[8];
    float4 av[8];
    auto issue = [&](const float* in, const float* w, int kc) {
#pragma unroll
        for (int i = 0; i < 4; i++) {
            const int c = kc + (sc2 + i * 8) * 2;
            bv[2 * i + 0] = *(const float4*)(in + (b * Cc + c) * HWn + hw0 + su * 4);
            bv[2 * i + 1] = *(const float4*)(in + (b * Cc + c + 1) * HWn + hw0 + su * 4);
        }
#pragma unroll
        for (int i = 0; i < 8; i++)
            av[i] = *(const float4*)(w + (ao + i * 16) * Cc + kc + au * 4);
    };

    auto stage_convert = [&]() {
#pragma unroll
        for (int i = 0; i < 4; i++) {
            const int c2 = sc2 + i * 8;
            const float4 v0 = bv[2 * i + 0];
            const float4 v1 = bv[2 * i + 1];
            uint4 pk;
            pk.x = (unsigned)f2bf(v0.x) | ((unsigned)f2bf(v1.x) << 16);
            pk.y = (unsigned)f2bf(v0.y) | ((unsigned)f2bf(v1.y) << 16);
            pk.z = (unsigned)f2bf(v0.z) | ((unsigned)f2bf(v1.z) << 16);
            pk.w = (unsigned)f2bf(v0.w) | ((unsigned)f2bf(v1.w) << 16);
            *(uint4*)&B_s[c2][su * 4] = pk;
        }
#pragma unroll
        for (int i = 0; i < 8; i++) {
            const int o = ao + i * 16;
            const float4 v = av[i];
            unsigned int lo = (unsigned)f2bf(v.x) | ((unsigned)f2bf(v.y) << 16);
            unsigned int hi = (unsigned)f2bf(v.z) | ((unsigned)f2bf(v.w) << 16);
            *(uint2*)&A_s[o][au * 4] = make_uint2(lo, hi);
        }
    };

    auto do_mfma = [&](f32x4 (&acc)[4][4]) {
#pragma unroll
        for (int ks = 0; ks < 2; ks++) {
            bf16x8 af[4];
#pragma unroll
            for (int mi = 0; mi < 4; mi++)
                af[mi] = *(const bf16x8*)&A_s[m0 + mi * 16 + r][ks * 32 + q * 8];
#pragma unroll
            for (int ni = 0; ni < 4; ni++) {
                unsigned int bw[4];
                const int nn = n0 + ni * 16 + r;
                const int row = ks * 16 + q * 4;
#pragma unroll
                for (int jj = 0; jj < 4; jj++) bw[jj] = B_s[row + jj][nn];
                const bf16x8 bfr = *(const bf16x8*)bw;
#pragma unroll
                for (int mi = 0; mi < 4; mi++)
                    acc[mi][ni] = __builtin_amdgcn_mfma_f32_16x16x32_bf16(af[mi], bfr, acc[mi][ni], 0, 0, 0);
            }
        }
    };

    // grid barrier: device-scope counter; all 512 blocks resident by construction
    auto gridbar = [&](unsigned* c) {
        __syncthreads();
        if (t == 0) {
            __threadfence();   // release: all prior stores/atomics visible device-wide
            __hip_atomic_fetch_add(c, 1u, __ATOMIC_ACQ_REL, __HIP_MEMORY_SCOPE_AGENT);
            long guard = 0;
            while (__hip_atomic_load(c, __ATOMIC_ACQUIRE, __HIP_MEMORY_SCOPE_AGENT) < GRID) {
                __builtin_amdgcn_s_sleep(8);
                if (++guard > (1L << 25)) break;   // fail loud, never hang
            }
        }
        __syncthreads();
        __threadfence();       // acquire side
    };

    // ---- phase A: two GEMMs, register-prefetch pipeline (proven structure) ----
    issue(gin, wgw, 0);
    for (int kc = 0; kc < Cc; kc += BK) {
        stage_convert();
        __syncthreads();
        if (kc + BK < Cc) issue(gin, wgw, kc + BK);
        else              issue(xin, wxw, 0);   // cross-GEMM prefetch
        do_mfma(accg);
        __syncthreads();
    }
    for (int kc = 0; kc < Cc; kc += BK) {
        stage_convert();
        __syncthreads();
        if (kc + BK < Cc) issue(xin, wxw, kc + BK);
        do_mfma(accx);
        __syncthreads();
    }

    // ---- phase B: BN1 stat partials -> gstat atomics ----
    const int hf = wv >> 1;
    auto stats_half = [&](f32x4 (&acc)[4][4], int z) {
#pragma unroll
        for (int mi = 0; mi < 4; mi++)
#pragma unroll
            for (int reg = 0; reg < 4; reg++) {
                const int o = m0 + mi * 16 + q * 4 + reg;
                float s1 = 0.f, s2 = 0.f;
#pragma unroll
                for (int ni = 0; ni < 4; ni++) {
                    const float v = acc[mi][ni][reg];
                    s1 += v; s2 += v * v;
                }
#pragma unroll
                for (int d = 1; d < 16; d <<= 1) {
                    s1 += __shfl_xor(s1, d);
                    s2 += __shfl_xor(s2, d);
                }
                if (r == 0) {
                    red[z * 4 + hf * 2 + 0][o] = s1;
                    red[z * 4 + hf * 2 + 1][o] = s2;
                }
            }
    };
    stats_half(accg, 0);
    stats_half(accx, 1);
    __syncthreads();
    for (int e = t; e < 512; e += 256) {
        const int zz = e >> 8, s = (e >> 7) & 1, o = e & 127;
        const float v = red[zz * 4 + s][o] + red[zz * 4 + 2 + s][o];
        atomicAdd(&gstat[(((zz << 7) | o) << 1) | s], v);   // device-scope
    }

    gridbar(&bar[0]);   // ================= BAR 1 =================

    // ---- phase C: every block builds the BN coef table ----
    if (t < 128) {
        const float s1g = __hip_atomic_load(&gstat[(t << 1) | 0], __ATOMIC_RELAXED, __HIP_MEMORY_SCOPE_AGENT);
        const float s2g = __hip_atomic_load(&gstat[(t << 1) | 1], __ATOMIC_RELAXED, __HIP_MEMORY_SCOPE_AGENT);
        const float s1x = __hip_atomic_load(&gstat[256 + ((t << 1) | 0)], __ATOMIC_RELAXED, __HIP_MEMORY_SCOPE_AGENT);
        const float s2x = __hip_atomic_load(&gstat[256 + ((t << 1) | 1)], __ATOMIC_RELAXED, __HIP_MEMORY_SCOPE_AGENT);
        const float invN = 1.f / (float)Ntot;
        const float mg = s1g * invN;
        const float vg = s2g * invN - mg * mg;
        const float gs = wg_gamma[t] * rsqrtf(vg + 1e-5f);
        const float gh = wg_beta[t] - mg * gs;
        const float mx = s1x * invN;
        const float vx = s2x * invN - mx * mx;
        const float xs = wx_gamma[t] * rsqrtf(vx + 1e-5f);
        const float xh = wx_beta[t] - mx * xs;
        lgs[t] = gs;
        lxs[t] = xs;
        lch[t] = gh + xh;
        lpw[t] = psi_w[t];
    }
    __syncthreads();

    // ---- phase D: psi from registers ----
    float part[4] = {0.f, 0.f, 0.f, 0.f};
#pragma unroll
    for (int mi = 0; mi < 4; mi++)
#pragma unroll
        for (int reg = 0; reg < 4; reg++) {
            const int o = m0 + mi * 16 + q * 4 + reg;
            const float gs = lgs[o], xs = lxs[o], ch = lch[o], pw = lpw[o];
#pragma unroll
            for (int ni = 0; ni < 4; ni++)
                part[ni] += pw * fmaxf(gs * accg[mi][ni][reg] + xs * accx[mi][ni][reg] + ch, 0.f);
        }
    const int gidx = (wv & 1) * 4 + q;
#pragma unroll
    for (int ni = 0; ni < 4; ni++)
        red[gidx][n0 + ni * 16 + r] = part[ni];
    __syncthreads();

    float ps1 = 0.f, ps2 = 0.f;
    if (t < 128) {
        float s = 0.f;
#pragma unroll
        for (int gI = 0; gI < 8; gI++) s += red[gI][t];
        sfin[t] = s;
        ps1 = s; ps2 = s * s;
    }
#pragma unroll
    for (int d = 1; d < 64; d <<= 1) {
        ps1 += __shfl_xor(ps1, d);
        ps2 += __shfl_xor(ps2, d);
    }
    __syncthreads();
    if (t < 128 && lane == 0) { rr[wv] = ps1; rr[2 + wv] = ps2; }
    __syncthreads();
    if (t == 0) {
        atomicAdd(&psum[0], rr[0] + rr[1]);
        atomicAdd(&psum[1], rr[2] + rr[3]);
    }

    gridbar(&bar[1]);   // ================= BAR 2 =================

    // ---- phase E: sigmoid coefs + final multiply ----
    if (t == 0) {
        const float S1 = __hip_atomic_load(&psum[0], __ATOMIC_RELAXED, __HIP_MEMORY_SCOPE_AGENT);
        const float S2 = __hip_atomic_load(&psum[1], __ATOMIC_RELAXED, __HIP_MEMORY_SCOPE_AGENT);
        const float invN = 1.f / (float)Ntot;
        const float m = S1 * invN;
        const float v = S2 * invN - m * m;
        const float psc = psi_gamma[0] * rsqrtf(v + 1e-5f);
        pcl[0] = psc;
        pcl[1] = psi_beta[0] - m * psc;
    }
    __syncthreads();

    const float psc = pcl[0], psh = pcl[1];
    float sig[4];
#pragma unroll
    for (int k = 0; k < 4; k++) {
        const float sv = sfin[su * 4 + k];
        sig[k] = 1.f / (1.f + __expf(-(psc * sv + psh)));
    }
    const float* xb = xin + (((size_t)(b * Cc)) << 12) + hw0 + su * 4;
    float* ob = outp + (((size_t)(b * Cc)) << 12) + hw0 + su * 4;
    const int c0 = t >> 5;
#pragma unroll 4
    for (int i = 0; i < 32; i++) {
        const size_t coff = ((size_t)(c0 + i * 8)) << 12;
        const float4 xv = *(const float4*)(xb + coff);
        float4 rv;
        rv.x = xv.x * sig[0];
        rv.y = xv.y * sig[1];
        rv.z = xv.z * sig[2];
        rv.w = xv.w * sig[3];
        *(float4*)(ob + coff) = rv;
    }
}

extern "C" void kernel_launch(void* const* d_in, const int* in_sizes, int n_in,
                              void* d_out, int out_size, void* d_ws, size_t ws_size,
                              hipStream_t stream)
{
    const float* g         = (const float*)d_in[0];
    const float* x         = (const float*)d_in[1];
    const float* wg_w      = (const float*)d_in[2];
    const float* wg_gamma  = (const float*)d_in[4];
    const float* wg_beta   = (const float*)d_in[5];
    const float* wx_w      = (const float*)d_in[6];
    const float* wx_gamma  = (const float*)d_in[8];
    const float* wx_beta   = (const float*)d_in[9];
    const float* psi_w     = (const float*)d_in[10];
    const float* psi_gamma = (const float*)d_in[12];
    const float* psi_beta  = (const float*)d_in[13];
    // biases d_in[3], d_in[7], d_in[11] cancel exactly under training-mode BN

    float* out = (float*)d_out;

    float* ws      = (float*)d_ws;
    float* gstat   = ws;                       // 512 floats
    float* psum    = ws + 512;                 // 2 floats
    unsigned* bar  = (unsigned*)(ws + 514);    // 2 counters
    // zero the sync/stat region (516 floats) each launch
    hipMemsetAsync(ws, 0, 516 * sizeof(float), stream);

    fused<<<dim3(GRID), 256, 0, stream>>>(
        g, x, wg_w, wx_w, wg_gamma, wg_beta, wx_gamma, wx_beta,
        psi_w, psi_gamma, psi_beta, out, gstat, psum, bar);
}

// Round 5
// 223.503 us; speedup vs baseline: 1.5484x; 1.5484x over previous
//
#include <hip/hip_runtime.h>
#include <hip/hip_bf16.h>
#include <math.h>

#define Bn 16
#define Cc 256
#define Oo 128
#define HWn 4096
#define Ntot 65536   // Bn*HWn
#define BK 64

typedef __attribute__((ext_vector_type(8))) __bf16 bf16x8;
typedef __attribute__((ext_vector_type(4))) float f32x4;

__device__ __forceinline__ unsigned short f2bf(float f) {
    unsigned u = __builtin_bit_cast(unsigned, f);
    u = (u + 0x7FFFu + ((u >> 16) & 1u)) >> 16;
    return (unsigned short)u;
}

__device__ __forceinline__ float bf2f(unsigned short h) {
    return __builtin_bit_cast(float, (unsigned)h << 16);
}

// ---------------- fused conv1x1 (bf16 MFMA) + per-channel partial stats ----------------
// z=0: tg = wg_w @ g ; z=1: tx = wx_w @ x   (biases cancel exactly under BN and are dropped)
// Output stored as bf16 [b][o][hw]. Stats computed from exact fp32 accumulators.
// Tile: M=128 (o) x N=128 (hw), K=256, BK=64. 4 waves in 2x2, each wave 64x64 (4x4 frags).
// Register-prefetch pipeline: loads for tile k+1 issued right after the LDS-ready barrier.
// PROVEN at 60 us (round 3) — unchanged this round.
__global__ __launch_bounds__(256, 2)
void conv_mfma(const float* __restrict__ gin, const float* __restrict__ xin,
               const float* __restrict__ wgw, const float* __restrict__ wxw,
               unsigned short* __restrict__ tg, unsigned short* __restrict__ tx,
               float* __restrict__ pstat)
{
    const int z = blockIdx.z;
    const float* in = z ? xin : gin;
    const float* w  = z ? wxw : wgw;
    unsigned short* out = z ? tx : tg;

    __shared__ short A_s[128][72];        // [o][c] bf16, row stride 144 B
    __shared__ unsigned int B_s[32][129]; // [c2][hw] packed (bf16 c, bf16 c+1), row 516 B

    const int t    = threadIdx.x;
    const int b    = blockIdx.y;
    const int hw0  = blockIdx.x * 128;
    const int lane = t & 63;
    const int wv   = t >> 6;
    const int m0   = (wv & 1) * 64;   // o offset in tile
    const int n0   = (wv >> 1) * 64;  // hw offset in tile
    const int q    = lane >> 4;
    const int r    = lane & 15;

    // staging indices
    const int su  = t & 31;   // B: hw block (hw = su*4)
    const int sc2 = t >> 5;   // B: c-pair row 0..7
    const int au  = t & 15;   // A: c block (c = au*4)
    const int ao  = t >> 4;   // A: o 0..15 (step 16)

    f32x4 acc[4][4];
#pragma unroll
    for (int i = 0; i < 4; i++)
#pragma unroll
        for (int j = 0; j < 4; j++) acc[i][j] = (f32x4){0.f, 0.f, 0.f, 0.f};

    // in-flight staging registers (one K-tile)
    float4 bv[8];
    float4 av[8];
    auto issue = [&](int kc) {
#pragma unroll
        for (int i = 0; i < 4; i++) {
            const int c = kc + (sc2 + i * 8) * 2;
            bv[2 * i + 0] = *(const float4*)(in + (b * Cc + c) * HWn + hw0 + su * 4);
            bv[2 * i + 1] = *(const float4*)(in + (b * Cc + c + 1) * HWn + hw0 + su * 4);
        }
#pragma unroll
        for (int i = 0; i < 8; i++)
            av[i] = *(const float4*)(w + (ao + i * 16) * Cc + kc + au * 4);
    };

    issue(0);

    for (int kc = 0; kc < Cc; kc += BK) {
        // convert staged regs -> LDS (compiler inserts the vmcnt waits)
#pragma unroll
        for (int i = 0; i < 4; i++) {
            const int c2 = sc2 + i * 8;
            const float4 v0 = bv[2 * i + 0];
            const float4 v1 = bv[2 * i + 1];
            uint4 pk;
            pk.x = (unsigned)f2bf(v0.x) | ((unsigned)f2bf(v1.x) << 16);
            pk.y = (unsigned)f2bf(v0.y) | ((unsigned)f2bf(v1.y) << 16);
            pk.z = (unsigned)f2bf(v0.z) | ((unsigned)f2bf(v1.z) << 16);
            pk.w = (unsigned)f2bf(v0.w) | ((unsigned)f2bf(v1.w) << 16);
            *(uint4*)&B_s[c2][su * 4] = pk;   // contiguous b128 write: conflict-free
        }
#pragma unroll
        for (int i = 0; i < 8; i++) {
            const int o = ao + i * 16;
            const float4 v = av[i];
            unsigned int lo = (unsigned)f2bf(v.x) | ((unsigned)f2bf(v.y) << 16);
            unsigned int hi = (unsigned)f2bf(v.z) | ((unsigned)f2bf(v.w) << 16);
            *(uint2*)&A_s[o][au * 4] = make_uint2(lo, hi);
        }
        __syncthreads();   // LDS ready

        // prefetch next K-tile while this tile's MFMA runs
        if (kc + BK < Cc) issue(kc + BK);

#pragma unroll
        for (int ks = 0; ks < 2; ks++) {
            bf16x8 af[4];
#pragma unroll
            for (int mi = 0; mi < 4; mi++)
                af[mi] = *(const bf16x8*)&A_s[m0 + mi * 16 + r][ks * 32 + q * 8];
#pragma unroll
            for (int ni = 0; ni < 4; ni++) {
                unsigned int bw[4];
                const int nn = n0 + ni * 16 + r;
                const int row = ks * 16 + q * 4;
#pragma unroll
                for (int jj = 0; jj < 4; jj++) bw[jj] = B_s[row + jj][nn];
                const bf16x8 bfr = *(const bf16x8*)bw;
#pragma unroll
                for (int mi = 0; mi < 4; mi++)
                    acc[mi][ni] = __builtin_amdgcn_mfma_f32_16x16x32_bf16(af[mi], bfr, acc[mi][ni], 0, 0, 0);
            }
        }
        __syncthreads();   // LDS consumed
    }

    // epilogue: store bf16, per-o stats -> LDS combine -> per-block partial store
    float* red = (float*)&A_s[0][0];   // 4*128 floats, reuse of A_s (all MFMA reads done)
    const int hf = wv >> 1;            // which n-half this wave covers
#pragma unroll
    for (int mi = 0; mi < 4; mi++) {
#pragma unroll
        for (int reg = 0; reg < 4; reg++) {
            const int o = m0 + mi * 16 + q * 4 + reg;
            float s1 = 0.f, s2 = 0.f;
#pragma unroll
            for (int ni = 0; ni < 4; ni++) {
                const float v = acc[mi][ni][reg];
                out[((b * Oo + o) << 12) + hw0 + n0 + ni * 16 + r] = f2bf(v);
                s1 += v; s2 += v * v;
            }
#pragma unroll
            for (int d = 1; d < 16; d <<= 1) {
                s1 += __shfl_xor(s1, d);
                s2 += __shfl_xor(s2, d);
            }
            if (r == 0) {
                red[(hf * 2 + 0) * 128 + o] = s1;
                red[(hf * 2 + 1) * 128 + o] = s2;
            }
        }
    }
    __syncthreads();
    {
        const int o = t & 127;
        const int s = t >> 7;
        const float v = red[(0 + s) * 128 + o] + red[(2 + s) * 128 + o];
        const int blk = blockIdx.y * 32 + blockIdx.x;
        pstat[(size_t)(((((z << 7) | o) << 1) | s) << 9) | blk] = v;
    }
}

// ---------------- reduce partial stats -> per-channel coefficient float4 ----------------
// 128 blocks, one per channel o. coef[o] = (gs, xs, gh+xh, psi_w[o])
__global__ void finalize1(const float* __restrict__ pstat,
                          const float* __restrict__ wg_gamma, const float* __restrict__ wg_beta,
                          const float* __restrict__ wx_gamma, const float* __restrict__ wx_beta,
                          const float* __restrict__ psi_w, float4* __restrict__ coef)
{
    const int o = blockIdx.x;
    const int t = threadIdx.x;
    const float* r00 = pstat + (size_t)(((0 * 128 + o) * 2 + 0)) * 512;
    const float* r01 = pstat + (size_t)(((0 * 128 + o) * 2 + 1)) * 512;
    const float* r10 = pstat + (size_t)(((1 * 128 + o) * 2 + 0)) * 512;
    const float* r11 = pstat + (size_t)(((1 * 128 + o) * 2 + 1)) * 512;
    float s1g = r00[t] + r00[t + 256];
    float s2g = r01[t] + r01[t + 256];
    float s1x = r10[t] + r10[t + 256];
    float s2x = r11[t] + r11[t + 256];
#pragma unroll
    for (int d = 1; d < 64; d <<= 1) {
        s1g += __shfl_xor(s1g, d);
        s2g += __shfl_xor(s2g, d);
        s1x += __shfl_xor(s1x, d);
        s2x += __shfl_xor(s2x, d);
    }
    __shared__ float rr[4][4];
    const int wv = t >> 6, lid = t & 63;
    if (lid == 0) { rr[0][wv] = s1g; rr[1][wv] = s2g; rr[2][wv] = s1x; rr[3][wv] = s2x; }
    __syncthreads();
    if (t == 0) {
        const float invN = 1.f / (float)Ntot;
        const float S1g = rr[0][0] + rr[0][1] + rr[0][2] + rr[0][3];
        const float S2g = rr[1][0] + rr[1][1] + rr[1][2] + rr[1][3];
        const float S1x = rr[2][0] + rr[2][1] + rr[2][2] + rr[2][3];
        const float S2x = rr[3][0] + rr[3][1] + rr[3][2] + rr[3][3];
        const float mg = S1g * invN;
        const float vg = S2g * invN - mg * mg;
        const float gs = wg_gamma[o] * rsqrtf(vg + 1e-5f);
        const float gh = wg_beta[o] - mg * gs;
        const float mx = S1x * invN;
        const float vx = S2x * invN - mx * mx;
        const float xs = wx_gamma[o] * rsqrtf(vx + 1e-5f);
        const float xh = wx_beta[o] - mx * xs;
        coef[o] = make_float4(gs, xs, gh + xh, psi_w[o]);
    }
}

// ---------------- psi: S[p] = sum_o pw*relu(gs*tg + xs*tx + ch), + stat partials ----------
// 1024 blocks x 256 threads: each block 64 pixels; 4 waves each cover 32 channels,
// LDS combine. 4 blocks/CU (16 waves/CU) -> latency-hidden L3-resident bf16 reads.
__global__ __launch_bounds__(256)
void psi_k(const unsigned short* __restrict__ tg, const unsigned short* __restrict__ tx,
           const float4* __restrict__ coef, float* __restrict__ S, float* __restrict__ pp)
{
    __shared__ float4 cf[128];
    __shared__ float sr[4][64];
    const int t    = threadIdx.x;
    const int lane = t & 63;
    const int wv   = t >> 6;
    if (t < 128) cf[t] = coef[t];
    __syncthreads();

    const int p  = blockIdx.x * 64 + lane;
    const int b  = p >> 12;
    const int hw = p & 4095;
    const size_t base = (((size_t)(b * Oo + wv * 32)) << 12) + hw;
    const unsigned short* gp = tg + base;
    const unsigned short* xp = tx + base;
    float s = 0.f;
#pragma unroll
    for (int oi = 0; oi < 32; oi++) {
        const float gv = bf2f(gp[(size_t)oi << 12]);
        const float xv = bf2f(xp[(size_t)oi << 12]);
        const float4 c = cf[wv * 32 + oi];   // broadcast read, conflict-free
        s += c.w * fmaxf(c.x * gv + c.y * xv + c.z, 0.f);
    }
    sr[wv][lane] = s;
    __syncthreads();
    if (wv == 0) {
        const float st = s + sr[1][lane] + sr[2][lane] + sr[3][lane];
        S[p] = st;   // psi bias cancels in BN2
        float s1 = st, s2 = st * st;
#pragma unroll
        for (int d = 1; d < 64; d <<= 1) {
            s1 += __shfl_xor(s1, d);
            s2 += __shfl_xor(s2, d);
        }
        if (lane == 0) {
            pp[blockIdx.x]        = s1;
            pp[1024 + blockIdx.x] = s2;
        }
    }
}

// ---------------- reduce psi stat partials (1024+1024) -> sigmoid scale/shift ----------------
__global__ void finalize2(const float* __restrict__ pp, const float* __restrict__ psi_gamma,
                          const float* __restrict__ psi_beta, float* __restrict__ pc)
{
    const int t = threadIdx.x;
    float s1 = pp[t] + pp[t + 256] + pp[t + 512] + pp[t + 768];
    float s2 = pp[1024 + t] + pp[1280 + t] + pp[1536 + t] + pp[1792 + t];
#pragma unroll
    for (int d = 1; d < 64; d <<= 1) {
        s1 += __shfl_xor(s1, d);
        s2 += __shfl_xor(s2, d);
    }
    __shared__ float a1[4], a2[4];
    const int wid = t >> 6, lid = t & 63;
    if (lid == 0) { a1[wid] = s1; a2[wid] = s2; }
    __syncthreads();
    if (t == 0) {
        const float invN = 1.f / (float)Ntot;
        const float S1 = a1[0] + a1[1] + a1[2] + a1[3];
        const float S2 = a2[0] + a2[1] + a2[2] + a2[3];
        const float m = S1 * invN;
        const float v = S2 * invN - m * m;
        const float ps = psi_gamma[0] * rsqrtf(v + 1e-5f);
        pc[0] = ps;
        pc[1] = psi_beta[0] - m * ps;
    }
}

// ---------------- out = x * sigmoid(pscale*s + pshift) ----------------
__global__ __launch_bounds__(256)
void final_mul_kernel(const float* __restrict__ x, const float* __restrict__ S,
                      const float* __restrict__ pc, float* __restrict__ out)
{
    const size_t i = ((size_t)blockIdx.x * 256 + threadIdx.x) * 4;
    const int hw = (int)(i & 4095);
    const size_t bc = i >> 12;
    const int b = (int)(bc >> 8);
    const float ps = pc[0], psh = pc[1];
    const float4 xv = *(const float4*)(x + i);
    const float4 sv = *(const float4*)(S + ((size_t)b << 12) + hw);
    float4 r;
    r.x = xv.x * (1.f / (1.f + __expf(-(ps * sv.x + psh))));
    r.y = xv.y * (1.f / (1.f + __expf(-(ps * sv.y + psh))));
    r.z = xv.z * (1.f / (1.f + __expf(-(ps * sv.z + psh))));
    r.w = xv.w * (1.f / (1.f + __expf(-(ps * sv.w + psh))));
    *(float4*)(out + i) = r;
}

extern "C" void kernel_launch(void* const* d_in, const int* in_sizes, int n_in,
                              void* d_out, int out_size, void* d_ws, size_t ws_size,
                              hipStream_t stream)
{
    const float* g         = (const float*)d_in[0];
    const float* x         = (const float*)d_in[1];
    const float* wg_w      = (const float*)d_in[2];
    const float* wg_gamma  = (const float*)d_in[4];
    const float* wg_beta   = (const float*)d_in[5];
    const float* wx_w      = (const float*)d_in[6];
    const float* wx_gamma  = (const float*)d_in[8];
    const float* wx_beta   = (const float*)d_in[9];
    const float* psi_w     = (const float*)d_in[10];
    const float* psi_gamma = (const float*)d_in[12];
    const float* psi_beta  = (const float*)d_in[13];
    // biases d_in[3], d_in[7], d_in[11] cancel exactly under training-mode BN

    float* out = (float*)d_out;
    // d_out doubles as scratch for the bf16 conv outputs (32 MB of its 64 MB),
    // fully overwritten by final_mul_kernel afterwards.
    unsigned short* tg = (unsigned short*)out;                         // 16 MB
    unsigned short* tx = (unsigned short*)out + (size_t)Bn * Oo * HWn; // next 16 MB

    float* ws    = (float*)d_ws;
    float* S     = ws;                          // 65536 floats
    float* pstat = ws + 65536;                  // 262144 floats: [(z,o,s) 512 rows][512 blocks]
    float4* coef = (float4*)(ws + 327680);      // 128 float4
    float* pp    = ws + 328192;                 // 2048 floats
    float* pc    = ws + 330240;                 // 2

    // no memsets: every buffer is fully written before being read

    conv_mfma<<<dim3(HWn / 128, Bn, 2), 256, 0, stream>>>(
        g, x, wg_w, wx_w, tg, tx, pstat);
    finalize1<<<128, 256, 0, stream>>>(pstat, wg_gamma, wg_beta, wx_gamma, wx_beta,
                                       psi_w, coef);
    psi_k<<<1024, 256, 0, stream>>>(tg, tx, coef, S, pp);
    finalize2<<<1, 256, 0, stream>>>(pp, psi_gamma, psi_beta, pc);
    final_mul_kernel<<<(Ntot * Cc) / (4 * 256), 256, 0, stream>>>(x, S, pc, out);
}

// Round 6
// 221.597 us; speedup vs baseline: 1.5617x; 1.0086x over previous
//
#include <hip/hip_runtime.h>
#include <hip/hip_bf16.h>
#include <math.h>

#define Bn 16
#define Cc 256
#define Oo 128
#define HWn 4096
#define Ntot 65536   // Bn*HWn
#define BK 64

typedef __attribute__((ext_vector_type(8))) __bf16 bf16x8;
typedef __attribute__((ext_vector_type(4))) float f32x4;

__device__ __forceinline__ float bf2f(unsigned short h) {
    return __builtin_bit_cast(float, (unsigned)h << 16);
}

// one-instruction packed f32x2 -> bf16x2 (RNE), low half = a
// non-volatile: pure value op, scheduler may reorder/interleave freely
__device__ __forceinline__ unsigned cvt_pk_bf16(float a, float b) {
    unsigned r;
    asm("v_cvt_pk_bf16_f32 %0, %1, %2" : "=v"(r) : "v"(a), "v"(b));
    return r;
}

// ---------------- fused conv1x1 (bf16 MFMA) + per-channel partial stats ----------------
// z=0: tg = wg_w @ g ; z=1: tx = wx_w @ x   (biases cancel exactly under BN and are dropped)
// Output stored as bf16 [b][o][hw]. Stats computed from exact fp32 accumulators.
// Tile: M=128 (o) x N=128 (hw), K=256, BK=64. 4 waves in 2x2, each wave 64x64 (4x4 frags).
// Register-prefetch pipeline: loads for tile k+1 issued right after the LDS-ready barrier.
// This round: B_s stride 129->130 (q-group bank offset 4 -> 8 banks: 2-way = free),
//             v_cvt_pk_bf16_f32 staging converts (1 instr per packed pair vs ~10).
__global__ __launch_bounds__(256, 2)
void conv_mfma(const float* __restrict__ gin, const float* __restrict__ xin,
               const float* __restrict__ wgw, const float* __restrict__ wxw,
               unsigned short* __restrict__ tg, unsigned short* __restrict__ tx,
               float* __restrict__ pstat)
{
    const int z = blockIdx.z;
    const float* in = z ? xin : gin;
    const float* w  = z ? wxw : wgw;
    unsigned short* out = z ? tx : tg;

    __shared__ short A_s[128][72];        // [o][c] bf16, row stride 144 B
    __shared__ unsigned int B_s[32][130]; // [c2][hw] packed (bf16 c, bf16 c+1), row 520 B

    const int t    = threadIdx.x;
    const int b    = blockIdx.y;
    const int hw0  = blockIdx.x * 128;
    const int lane = t & 63;
    const int wv   = t >> 6;
    const int m0   = (wv & 1) * 64;   // o offset in tile
    const int n0   = (wv >> 1) * 64;  // hw offset in tile
    const int q    = lane >> 4;
    const int r    = lane & 15;

    // staging indices
    const int su  = t & 31;   // B: hw block (hw = su*4)
    const int sc2 = t >> 5;   // B: c-pair row 0..7
    const int au  = t & 15;   // A: c block (c = au*4)
    const int ao  = t >> 4;   // A: o 0..15 (step 16)

    f32x4 acc[4][4];
#pragma unroll
    for (int i = 0; i < 4; i++)
#pragma unroll
        for (int j = 0; j < 4; j++) acc[i][j] = (f32x4){0.f, 0.f, 0.f, 0.f};

    // in-flight staging registers (one K-tile)
    float4 bv[8];
    float4 av[8];
    auto issue = [&](int kc) {
#pragma unroll
        for (int i = 0; i < 4; i++) {
            const int c = kc + (sc2 + i * 8) * 2;
            bv[2 * i + 0] = *(const float4*)(in + (b * Cc + c) * HWn + hw0 + su * 4);
            bv[2 * i + 1] = *(const float4*)(in + (b * Cc + c + 1) * HWn + hw0 + su * 4);
        }
#pragma unroll
        for (int i = 0; i < 8; i++)
            av[i] = *(const float4*)(w + (ao + i * 16) * Cc + kc + au * 4);
    };

    issue(0);

    for (int kc = 0; kc < Cc; kc += BK) {
        // convert staged regs -> LDS (compiler inserts the vmcnt waits)
#pragma unroll
        for (int i = 0; i < 4; i++) {
            const int c2 = sc2 + i * 8;
            const float4 v0 = bv[2 * i + 0];
            const float4 v1 = bv[2 * i + 1];
            uint4 pk;
            pk.x = cvt_pk_bf16(v0.x, v1.x);
            pk.y = cvt_pk_bf16(v0.y, v1.y);
            pk.z = cvt_pk_bf16(v0.z, v1.z);
            pk.w = cvt_pk_bf16(v0.w, v1.w);
            *(uint4*)&B_s[c2][su * 4] = pk;   // contiguous b128 write
        }
#pragma unroll
        for (int i = 0; i < 8; i++) {
            const int o = ao + i * 16;
            const float4 v = av[i];
            *(uint2*)&A_s[o][au * 4] =
                make_uint2(cvt_pk_bf16(v.x, v.y), cvt_pk_bf16(v.z, v.w));
        }
        __syncthreads();   // LDS ready

        // prefetch next K-tile while this tile's MFMA runs
        if (kc + BK < Cc) issue(kc + BK);

#pragma unroll
        for (int ks = 0; ks < 2; ks++) {
            bf16x8 af[4];
#pragma unroll
            for (int mi = 0; mi < 4; mi++)
                af[mi] = *(const bf16x8*)&A_s[m0 + mi * 16 + r][ks * 32 + q * 8];
#pragma unroll
            for (int ni = 0; ni < 4; ni++) {
                unsigned int bw[4];
                const int nn = n0 + ni * 16 + r;
                const int row = ks * 16 + q * 4;
#pragma unroll
                for (int jj = 0; jj < 4; jj++) bw[jj] = B_s[row + jj][nn];
                const bf16x8 bfr = *(const bf16x8*)bw;
#pragma unroll
                for (int mi = 0; mi < 4; mi++)
                    acc[mi][ni] = __builtin_amdgcn_mfma_f32_16x16x32_bf16(af[mi], bfr, acc[mi][ni], 0, 0, 0);
            }
        }
        __syncthreads();   // LDS consumed
    }

    // epilogue: store bf16, per-o stats -> LDS combine -> per-block partial store
    float* red = (float*)&A_s[0][0];   // 4*128 floats, reuse of A_s (all MFMA reads done)
    const int hf = wv >> 1;            // which n-half this wave covers
#pragma unroll
    for (int mi = 0; mi < 4; mi++) {
#pragma unroll
        for (int reg = 0; reg < 4; reg++) {
            const int o = m0 + mi * 16 + q * 4 + reg;
            float s1 = 0.f, s2 = 0.f;
#pragma unroll
            for (int ni = 0; ni < 4; ni++) {
                const float v = acc[mi][ni][reg];
                out[((b * Oo + o) << 12) + hw0 + n0 + ni * 16 + r] =
                    (unsigned short)cvt_pk_bf16(v, v);
                s1 += v; s2 += v * v;
            }
#pragma unroll
            for (int d = 1; d < 16; d <<= 1) {
                s1 += __shfl_xor(s1, d);
                s2 += __shfl_xor(s2, d);
            }
            if (r == 0) {
                red[(hf * 2 + 0) * 128 + o] = s1;
                red[(hf * 2 + 1) * 128 + o] = s2;
            }
        }
    }
    __syncthreads();
    {
        const int o = t & 127;
        const int s = t >> 7;
        const float v = red[(0 + s) * 128 + o] + red[(2 + s) * 128 + o];
        const int blk = blockIdx.y * 32 + blockIdx.x;
        pstat[(size_t)(((((z << 7) | o) << 1) | s) << 9) | blk] = v;
    }
}

// ---------------- reduce partial stats -> per-channel coefficient float4 ----------------
// 128 blocks, one per channel o. coef[o] = (gs, xs, gh+xh, psi_w[o])
__global__ void finalize1(const float* __restrict__ pstat,
                          const float* __restrict__ wg_gamma, const float* __restrict__ wg_beta,
                          const float* __restrict__ wx_gamma, const float* __restrict__ wx_beta,
                          const float* __restrict__ psi_w, float4* __restrict__ coef)
{
    const int o = blockIdx.x;
    const int t = threadIdx.x;
    const float* r00 = pstat + (size_t)(((0 * 128 + o) * 2 + 0)) * 512;
    const float* r01 = pstat + (size_t)(((0 * 128 + o) * 2 + 1)) * 512;
    const float* r10 = pstat + (size_t)(((1 * 128 + o) * 2 + 0)) * 512;
    const float* r11 = pstat + (size_t)(((1 * 128 + o) * 2 + 1)) * 512;
    float s1g = r00[t] + r00[t + 256];
    float s2g = r01[t] + r01[t + 256];
    float s1x = r10[t] + r10[t + 256];
    float s2x = r11[t] + r11[t + 256];
#pragma unroll
    for (int d = 1; d < 64; d <<= 1) {
        s1g += __shfl_xor(s1g, d);
        s2g += __shfl_xor(s2g, d);
        s1x += __shfl_xor(s1x, d);
        s2x += __shfl_xor(s2x, d);
    }
    __shared__ float rr[4][4];
    const int wv = t >> 6, lid = t & 63;
    if (lid == 0) { rr[0][wv] = s1g; rr[1][wv] = s2g; rr[2][wv] = s1x; rr[3][wv] = s2x; }
    __syncthreads();
    if (t == 0) {
        const float invN = 1.f / (float)Ntot;
        const float S1g = rr[0][0] + rr[0][1] + rr[0][2] + rr[0][3];
        const float S2g = rr[1][0] + rr[1][1] + rr[1][2] + rr[1][3];
        const float S1x = rr[2][0] + rr[2][1] + rr[2][2] + rr[2][3];
        const float S2x = rr[3][0] + rr[3][1] + rr[3][2] + rr[3][3];
        const float mg = S1g * invN;
        const float vg = S2g * invN - mg * mg;
        const float gs = wg_gamma[o] * rsqrtf(vg + 1e-5f);
        const float gh = wg_beta[o] - mg * gs;
        const float mx = S1x * invN;
        const float vx = S2x * invN - mx * mx;
        const float xs = wx_gamma[o] * rsqrtf(vx + 1e-5f);
        const float xh = wx_beta[o] - mx * xs;
        coef[o] = make_float4(gs, xs, gh + xh, psi_w[o]);
    }
}

// ---------------- psi: S[p] = sum_o pw*relu(gs*tg + xs*tx + ch), + stat partials ----------
// 1024 blocks x 256 threads: each block 64 pixels; 4 waves each cover 32 channels,
// LDS combine. 4 blocks/CU (16 waves/CU) -> latency-hidden L3-resident bf16 reads.
__global__ __launch_bounds__(256)
void psi_k(const unsigned short* __restrict__ tg, const unsigned short* __restrict__ tx,
           const float4* __restrict__ coef, float* __restrict__ S, float* __restrict__ pp)
{
    __shared__ float4 cf[128];
    __shared__ float sr[4][64];
    const int t    = threadIdx.x;
    const int lane = t & 63;
    const int wv   = t >> 6;
    if (t < 128) cf[t] = coef[t];
    __syncthreads();

    const int p  = blockIdx.x * 64 + lane;
    const int b  = p >> 12;
    const int hw = p & 4095;
    const size_t base = (((size_t)(b * Oo + wv * 32)) << 12) + hw;
    const unsigned short* gp = tg + base;
    const unsigned short* xp = tx + base;
    float s = 0.f;
#pragma unroll
    for (int oi = 0; oi < 32; oi++) {
        const float gv = bf2f(gp[(size_t)oi << 12]);
        const float xv = bf2f(xp[(size_t)oi << 12]);
        const float4 c = cf[wv * 32 + oi];   // broadcast read, conflict-free
        s += c.w * fmaxf(c.x * gv + c.y * xv + c.z, 0.f);
    }
    sr[wv][lane] = s;
    __syncthreads();
    if (wv == 0) {
        const float st = s + sr[1][lane] + sr[2][lane] + sr[3][lane];
        S[p] = st;   // psi bias cancels in BN2
        float s1 = st, s2 = st * st;
#pragma unroll
        for (int d = 1; d < 64; d <<= 1) {
            s1 += __shfl_xor(s1, d);
            s2 += __shfl_xor(s2, d);
        }
        if (lane == 0) {
            pp[blockIdx.x]        = s1;
            pp[1024 + blockIdx.x] = s2;
        }
    }
}

// ---------------- reduce psi stat partials (1024+1024) -> sigmoid scale/shift ----------------
__global__ void finalize2(const float* __restrict__ pp, const float* __restrict__ psi_gamma,
                          const float* __restrict__ psi_beta, float* __restrict__ pc)
{
    const int t = threadIdx.x;
    float s1 = pp[t] + pp[t + 256] + pp[t + 512] + pp[t + 768];
    float s2 = pp[1024 + t] + pp[1280 + t] + pp[1536 + t] + pp[1792 + t];
#pragma unroll
    for (int d = 1; d < 64; d <<= 1) {
        s1 += __shfl_xor(s1, d);
        s2 += __shfl_xor(s2, d);
    }
    __shared__ float a1[4], a2[4];
    const int wid = t >> 6, lid = t & 63;
    if (lid == 0) { a1[wid] = s1; a2[wid] = s2; }
    __syncthreads();
    if (t == 0) {
        const float invN = 1.f / (float)Ntot;
        const float S1 = a1[0] + a1[1] + a1[2] + a1[3];
        const float S2 = a2[0] + a2[1] + a2[2] + a2[3];
        const float m = S1 * invN;
        const float v = S2 * invN - m * m;
        const float ps = psi_gamma[0] * rsqrtf(v + 1e-5f);
        pc[0] = ps;
        pc[1] = psi_beta[0] - m * ps;
    }
}

// ---------------- out = x * sigmoid(pscale*s + pshift) ----------------
__global__ __launch_bounds__(256)
void final_mul_kernel(const float* __restrict__ x, const float* __restrict__ S,
                      const float* __restrict__ pc, float* __restrict__ out)
{
    const size_t i = ((size_t)blockIdx.x * 256 + threadIdx.x) * 4;
    const int hw = (int)(i & 4095);
    const size_t bc = i >> 12;
    const int b = (int)(bc >> 8);
    const float ps = pc[0], psh = pc[1];
    const float4 xv = *(const float4*)(x + i);
    const float4 sv = *(const float4*)(S + ((size_t)b << 12) + hw);
    float4 r;
    r.x = xv.x * (1.f / (1.f + __expf(-(ps * sv.x + psh))));
    r.y = xv.y * (1.f / (1.f + __expf(-(ps * sv.y + psh))));
    r.z = xv.z * (1.f / (1.f + __expf(-(ps * sv.z + psh))));
    r.w = xv.w * (1.f / (1.f + __expf(-(ps * sv.w + psh))));
    *(float4*)(out + i) = r;
}

extern "C" void kernel_launch(void* const* d_in, const int* in_sizes, int n_in,
                              void* d_out, int out_size, void* d_ws, size_t ws_size,
                              hipStream_t stream)
{
    const float* g         = (const float*)d_in[0];
    const float* x         = (const float*)d_in[1];
    const float* wg_w      = (const float*)d_in[2];
    const float* wg_gamma  = (const float*)d_in[4];
    const float* wg_beta   = (const float*)d_in[5];
    const float* wx_w      = (const float*)d_in[6];
    const float* wx_gamma  = (const float*)d_in[8];
    const float* wx_beta   = (const float*)d_in[9];
    const float* psi_w     = (const float*)d_in[10];
    const float* psi_gamma = (const float*)d_in[12];
    const float* psi_beta  = (const float*)d_in[13];
    // biases d_in[3], d_in[7], d_in[11] cancel exactly under training-mode BN

    float* out = (float*)d_out;
    // d_out doubles as scratch for the bf16 conv outputs (32 MB of its 64 MB),
    // fully overwritten by final_mul_kernel afterwards.
    unsigned short* tg = (unsigned short*)out;                         // 16 MB
    unsigned short* tx = (unsigned short*)out + (size_t)Bn * Oo * HWn; // next 16 MB

    float* ws    = (float*)d_ws;
    float* S     = ws;                          // 65536 floats
    float* pstat = ws + 65536;                  // 262144 floats: [(z,o,s) 512 rows][512 blocks]
    float4* coef = (float4*)(ws + 327680);      // 128 float4
    float* pp    = ws + 328192;                 // 2048 floats
    float* pc    = ws + 330240;                 // 2

    // no memsets: every buffer is fully written before being read

    conv_mfma<<<dim3(HWn / 128, Bn, 2), 256, 0, stream>>>(
        g, x, wg_w, wx_w, tg, tx, pstat);
    finalize1<<<128, 256, 0, stream>>>(pstat, wg_gamma, wg_beta, wx_gamma, wx_beta,
                                       psi_w, coef);
    psi_k<<<1024, 256, 0, stream>>>(tg, tx, coef, S, pp);
    finalize2<<<1, 256, 0, stream>>>(pp, psi_gamma, psi_beta, pc);
    final_mul_kernel<<<(Ntot * Cc) / (4 * 256), 256, 0, stream>>>(x, S, pc, out);
}